// Round 1
// baseline (65.381 us; speedup 1.0000x reference)
//
#include <hip/hip_runtime.h>
#include <hip/hip_bf16.h>

#define BDIM 256
#define NROW 64      // S = O = 64
#define DDIM 512
#define BK 128
#define NCHUNK 4     // 512/128
#define LDK 136      // BK + 8 bf16 pad (16B) -> breaks 256B-stride bank clustering
#define FDIM 32
#define BBATCH 32

typedef short bf16x8 __attribute__((ext_vector_type(8)));
typedef float f32x4 __attribute__((ext_vector_type(4)));

__device__ __forceinline__ unsigned short f2bf(float f) {
    unsigned int u = __float_as_uint(f);
    u += 0x7FFFu + ((u >> 16) & 1u);   // round-to-nearest-even
    return (unsigned short)(u >> 16);
}

__global__ __launch_bounds__(BDIM) void pwl_main(
        const float* __restrict__ pred, const float* __restrict__ slots,
        const int* __restrict__ labels, const unsigned char* __restrict__ vmask,
        float* __restrict__ gacc) {
    __shared__ unsigned short lA[NROW][LDK];   // slots chunk (bf16 bits)
    __shared__ unsigned short lB[NROW][LDK];   // pred chunk  (bf16 bits)
    __shared__ float simbuf[NROW][65];
    __shared__ float rnA[NROW], rnB[NROW];
    __shared__ float red_f;
    __shared__ int   red_i;

    const int t   = threadIdx.x;
    const int bid = blockIdx.x;          // bid = b*F + f  (matches [B,F,...] layout)
    const int b   = bid >> 5;
    const int f   = bid & 31;
    const float* gA = slots + (size_t)bid * NROW * DDIM;
    const float* gB = pred  + (size_t)bid * NROW * DDIM;

    const int lane = t & 63;
    const int w    = t >> 6;
    const int wr   = (w >> 1) * 32;      // s-quadrant base
    const int wc   = (w & 1) * 32;       // o-quadrant base
    const int lr   = lane & 15;
    const int lk   = (lane >> 4) * 8;

    f32x4 acc00 = {0,0,0,0}, acc01 = {0,0,0,0}, acc10 = {0,0,0,0}, acc11 = {0,0,0,0};
    float sa[8], sb[8];
#pragma unroll
    for (int i = 0; i < 8; ++i) { sa[i] = 0.f; sb[i] = 0.f; }

    for (int c = 0; c < NCHUNK; ++c) {
        if (c) __syncthreads();          // prev MFMA reads done before overwrite
        const int cbase = c * BK;
#pragma unroll
        for (int i = 0; i < 8; ++i) {
            const int row = i * 8 + (t >> 5);
            const int c4  = t & 31;
            const float4 va = *reinterpret_cast<const float4*>(gA + row * DDIM + cbase + c4 * 4);
            const float4 vb = *reinterpret_cast<const float4*>(gB + row * DDIM + cbase + c4 * 4);
            sa[i] += va.x*va.x + va.y*va.y + va.z*va.z + va.w*va.w;
            sb[i] += vb.x*vb.x + vb.y*vb.y + vb.z*vb.z + vb.w*vb.w;
            ushort4 ua, ub;
            ua.x = f2bf(va.x); ua.y = f2bf(va.y); ua.z = f2bf(va.z); ua.w = f2bf(va.w);
            ub.x = f2bf(vb.x); ub.y = f2bf(vb.y); ub.z = f2bf(vb.z); ub.w = f2bf(vb.w);
            *reinterpret_cast<ushort4*>(&lA[row][c4 * 4]) = ua;
            *reinterpret_cast<ushort4*>(&lB[row][c4 * 4]) = ub;
        }
        __syncthreads();
#pragma unroll
        for (int kk = 0; kk < 4; ++kk) {
            const int kb = kk * 32 + lk;
            const bf16x8 a0 = *reinterpret_cast<const bf16x8*>(&lA[wr      + lr][kb]);
            const bf16x8 a1 = *reinterpret_cast<const bf16x8*>(&lA[wr + 16 + lr][kb]);
            const bf16x8 b0 = *reinterpret_cast<const bf16x8*>(&lB[wc      + lr][kb]);
            const bf16x8 b1 = *reinterpret_cast<const bf16x8*>(&lB[wc + 16 + lr][kb]);
            acc00 = __builtin_amdgcn_mfma_f32_16x16x32_bf16(a0, b0, acc00, 0, 0, 0);
            acc01 = __builtin_amdgcn_mfma_f32_16x16x32_bf16(a0, b1, acc01, 0, 0, 0);
            acc10 = __builtin_amdgcn_mfma_f32_16x16x32_bf16(a1, b0, acc10, 0, 0, 0);
            acc11 = __builtin_amdgcn_mfma_f32_16x16x32_bf16(a1, b1, acc11, 0, 0, 0);
        }
    }

    // row sum-of-squares -> reciprocal norms (reduce across 32-lane halves)
#pragma unroll
    for (int i = 0; i < 8; ++i) {
        float x = sa[i], y = sb[i];
#pragma unroll
        for (int m = 1; m <= 16; m <<= 1) { x += __shfl_xor(x, m); y += __shfl_xor(y, m); }
        if ((t & 31) == 0) {
            const int row = i * 8 + (t >> 5);
            rnA[row] = 1.f / fmaxf(sqrtf(x), 1e-12f);
            rnB[row] = 1.f / fmaxf(sqrtf(y), 1e-12f);
        }
    }
    if (t == 0) { red_f = 0.f; red_i = 0; }
    __syncthreads();

    // normalize accumulators, write sim to LDS (C/D layout: col=lane&15, row=(lane>>4)*4+j)
    {
        const int r0 = wr + (lane >> 4) * 4;
        const int c0 = wc + lr;
#pragma unroll
        for (int j = 0; j < 4; ++j) {
            simbuf[r0 + j     ][c0     ] = acc00[j] * rnA[r0 + j     ] * rnB[c0     ];
            simbuf[r0 + j     ][c0 + 16] = acc01[j] * rnA[r0 + j     ] * rnB[c0 + 16];
            simbuf[r0 + 16 + j][c0     ] = acc10[j] * rnA[r0 + 16 + j] * rnB[c0     ];
            simbuf[r0 + 16 + j][c0 + 16] = acc11[j] * rnA[r0 + 16 + j] * rnB[c0 + 16];
        }
    }
    __syncthreads();

    // softmax over objects + focal at label; 4 lanes per s-row
    {
        const int s = t >> 2;
        const int q = t & 3;
        float v[16];
        float mx = -1e30f;
#pragma unroll
        for (int jj = 0; jj < 16; ++jj) {
            v[jj] = simbuf[s][q * 16 + jj];
            mx = fmaxf(mx, v[jj]);
        }
        mx = fmaxf(mx, __shfl_xor(mx, 1));
        mx = fmaxf(mx, __shfl_xor(mx, 2));
        float se = 0.f;
#pragma unroll
        for (int jj = 0; jj < 16; ++jj) se += __expf(v[jj] - mx);
        se += __shfl_xor(se, 1);
        se += __shfl_xor(se, 2);
        if (q == 0) {
            const int lab = labels[(f * BBATCH + b) * NROW + s];
            if (lab >= 0) {
                const float simt  = simbuf[s][lab];
                const float pt    = __expf(simt - mx) / se;
                const float u     = 1.f - pt + 1e-12f;
                const float focal = u * u * __logf(pt + 1e-12f);
                atomicAdd(&red_f, focal);
                atomicAdd(&red_i, 1);
            }
        }
    }
    __syncthreads();
    if (t == 0) {
        const float cnt = fmaxf((float)red_i, 1.f);
        const float nll = -red_f / cnt;
        const float vv  = vmask[f * BBATCH + b] ? 1.f : 0.f;
        atomicAdd(gacc, 100.f * nll * vv);
    }
}

__global__ __launch_bounds__(BDIM) void pwl_finalize(
        const unsigned char* __restrict__ vmask, const float* __restrict__ gacc,
        float* __restrict__ out) {
    __shared__ int ssum;
    const int t = threadIdx.x;
    if (t == 0) ssum = 0;
    __syncthreads();
    int loc = 0;
    for (int i = t; i < FDIM * BBATCH; i += BDIM) loc += (vmask[i] != 0) ? 1 : 0;
    atomicAdd(&ssum, loc);
    __syncthreads();
    if (t == 0) {
        const float sums = (float)ssum;
        const float loss = *gacc;
        out[0] = (sums > 0.f) ? loss / (32.0f * sums) : loss;
    }
}

extern "C" void kernel_launch(void* const* d_in, const int* in_sizes, int n_in,
                              void* d_out, int out_size, void* d_ws, size_t ws_size,
                              hipStream_t stream) {
    const float* pred          = (const float*)d_in[0];
    const float* slots         = (const float*)d_in[1];
    const int* labels          = (const int*)d_in[2];
    const unsigned char* vmask = (const unsigned char*)d_in[3];
    float* out  = (float*)d_out;
    float* gacc = (float*)d_ws;

    hipMemsetAsync(gacc, 0, sizeof(float), stream);
    pwl_main<<<dim3(BBATCH * FDIM), dim3(BDIM), 0, stream>>>(pred, slots, labels, vmask, gacc);
    pwl_finalize<<<dim3(1), dim3(BDIM), 0, stream>>>(vmask, gacc, out);
}